// Round 1
// baseline (1255.580 us; speedup 1.0000x reference)
//
#include <hip/hip_runtime.h>
#include <math.h>

#define HW   16384
#define Hh   128
#define Ww   128
#define Cc   256
#define CO   256
#define KK   9

// ---------------- Kernel 1: weight transpose (o,c,k) -> (c*9+k, o) ----------------
__global__ void k_wt(const float* __restrict__ w, float* __restrict__ wt) {
    int idx = blockIdx.x * 256 + threadIdx.x;      // over (c*9+k)*256 + o
    if (idx >= Cc * KK * CO) return;
    int o  = idx & 255;
    int ck = idx >> 8;                             // c*9+k
    int c  = ck / 9;
    int k  = ck - c * 9;
    wt[idx] = w[(o * Cc + c) * 9 + k];
}

// ---------------- Kernel 2: offset conv 3x3, 27 output channels ----------------
// grid: (256 = b*128+h, 27 = oc), block: 128 threads (w)
__global__ void k_offconv(const float* __restrict__ x, const float* __restrict__ wof,
                          const float* __restrict__ bof, float* __restrict__ om) {
    int w  = threadIdx.x;
    int bh = blockIdx.x;
    int b  = bh >> 7;
    int h  = bh & 127;
    int oc = blockIdx.y;

    float acc = bof[oc];
    const float* xb = x + (size_t)b * Cc * HW;
    const float* wk0 = wof + (size_t)oc * Cc * 9;

    for (int c = 0; c < Cc; ++c) {
        const float* xc = xb + c * HW;
        const float* wk = wk0 + c * 9;
        #pragma unroll
        for (int dh = -1; dh <= 1; ++dh) {
            int hy = h + dh;
            if (hy < 0 || hy > 127) continue;
            const float* xr = xc + hy * 128;
            #pragma unroll
            for (int dw = -1; dw <= 1; ++dw) {
                int wx = w + dw;
                if (wx < 0 || wx > 127) continue;
                acc = fmaf(xr[wx], wk[(dh + 1) * 3 + (dw + 1)], acc);
            }
        }
    }
    om[((size_t)b * 27 + oc) * HW + h * 128 + w] = acc;
}

// ---------------- Kernel 3: fused deform-gather + GEMM ----------------
// block: 256 threads; each block: one b, one h row, 32 w positions, all 256 o.
// thread: to = tid&63 -> 4 consecutive o; tj = tid>>6 -> 8 consecutive j.
__global__ __launch_bounds__(256) void k_main(const float* __restrict__ x,
                                              const float* __restrict__ om,
                                              const float* __restrict__ wt,
                                              const float* __restrict__ bias,
                                              float* __restrict__ y) {
    __shared__ float s_lds[32][32];
    __shared__ float w_lds[32][256];
    __shared__ int   c_off[32][4];
    __shared__ float c_w[32][4];

    const int tid  = threadIdx.x;
    const int bidx = blockIdx.x;                 // b*512 + h*4 + wt4
    const int wt4  = bidx & 3;
    const int h    = (bidx >> 2) & 127;
    const int b    = bidx >> 9;
    const int w0   = wt4 * 32;

    const int to = tid & 63;
    const int tj = tid >> 6;

    float acc[4][8];
    #pragma unroll
    for (int oi = 0; oi < 4; ++oi)
        #pragma unroll
        for (int ji = 0; ji < 8; ++ji) acc[oi][ji] = 0.0f;

    const float* xb = x + (size_t)b * Cc * HW;
    const size_t ombase = (size_t)b * 27 * HW;

    for (int k = 0; k < KK; ++k) {
        // ---- stage bilinear coords + weights (incl. sigmoid mask) for 32 positions ----
        if (tid < 32) {
            int j  = tid;
            int hw = h * 128 + w0 + j;
            float oy = om[ombase + (size_t)k * HW + hw];
            float ox = om[ombase + (size_t)(9 + k) * HW + hw];
            float mv = om[ombase + (size_t)(18 + k) * HW + hw];
            mv = 1.0f / (1.0f + expf(-mv));
            float py = (float)h - 1.0f + (float)(k / 3) + oy;
            float px = (float)(w0 + j) - 1.0f + (float)(k % 3) + ox;
            float y0f = floorf(py), x0f = floorf(px);
            float wy = py - y0f, wx = px - x0f;
            int iy = (int)y0f, ix = (int)x0f;
            float ww[4] = {(1.0f - wy) * (1.0f - wx), (1.0f - wy) * wx,
                           wy * (1.0f - wx),          wy * wx};
            const int dy[4] = {0, 0, 1, 1};
            const int dx[4] = {0, 1, 0, 1};
            #pragma unroll
            for (int r = 0; r < 4; ++r) {
                int yy = iy + dy[r], xx = ix + dx[r];
                bool v = (yy >= 0) && (yy <= 127) && (xx >= 0) && (xx <= 127);
                int yc = min(max(yy, 0), 127);
                int xc = min(max(xx, 0), 127);
                c_off[j][r] = yc * 128 + xc;
                c_w[j][r]   = v ? ww[r] * mv : 0.0f;
            }
        }
        __syncthreads();

        for (int c0 = 0; c0 < Cc; c0 += 32) {
            // ---- stage W tile: w_lds[c][o] for c in chunk, all o ----
            const float* wsrc = wt + ((size_t)c0 * 9 + k) * 256 + tid;
            #pragma unroll
            for (int c = 0; c < 32; ++c)
                w_lds[c][tid] = wsrc[(size_t)c * 9 * 256];

            // ---- stage S tile: gather s_lds[c][j] ----
            {
                int j     = tid & 31;
                int cbase = tid >> 5;
                #pragma unroll
                for (int i = 0; i < 4; ++i) {
                    int c = cbase + 8 * i;
                    const float* xc = xb + (size_t)(c0 + c) * HW;
                    float v = c_w[j][0] * xc[c_off[j][0]]
                            + c_w[j][1] * xc[c_off[j][1]]
                            + c_w[j][2] * xc[c_off[j][2]]
                            + c_w[j][3] * xc[c_off[j][3]];
                    s_lds[c][j] = v;
                }
            }
            __syncthreads();

            // ---- FMA: 4o x 8j register tile ----
            #pragma unroll 4
            for (int c = 0; c < 32; ++c) {
                const float4 wv = *(const float4*)&w_lds[c][to * 4];
                const float4 sa = *(const float4*)&s_lds[c][tj * 8];
                const float4 sb = *(const float4*)&s_lds[c][tj * 8 + 4];
                float wvv[4] = {wv.x, wv.y, wv.z, wv.w};
                float sv[8]  = {sa.x, sa.y, sa.z, sa.w, sb.x, sb.y, sb.z, sb.w};
                #pragma unroll
                for (int oi = 0; oi < 4; ++oi)
                    #pragma unroll
                    for (int ji = 0; ji < 8; ++ji)
                        acc[oi][ji] = fmaf(wvv[oi], sv[ji], acc[oi][ji]);
            }
            __syncthreads();
        }
    }

    // ---- epilogue: add bias, write y ----
    #pragma unroll
    for (int oi = 0; oi < 4; ++oi) {
        int o = to * 4 + oi;
        float bb = bias[o];
        float* yo = y + ((size_t)b * CO + o) * HW + h * 128 + w0 + tj * 8;
        float4 v0 = make_float4(acc[oi][0] + bb, acc[oi][1] + bb, acc[oi][2] + bb, acc[oi][3] + bb);
        float4 v1 = make_float4(acc[oi][4] + bb, acc[oi][5] + bb, acc[oi][6] + bb, acc[oi][7] + bb);
        *(float4*)&yo[0] = v0;
        *(float4*)&yo[4] = v1;
    }
}

// ---------------- Kernel 4: per-channel mean/var ----------------
__global__ void k_stats(const float* __restrict__ y, float* __restrict__ stats) {
    int o   = blockIdx.x;
    int tid = threadIdx.x;
    float s = 0.0f, sq = 0.0f;
    const float* y0 = y + (size_t)o * HW;
    const float* y1 = y + (size_t)(CO + o) * HW;
    for (int i = tid; i < HW; i += 256) {
        float v = y0[i]; s += v; sq += v * v;
        v = y1[i];       s += v; sq += v * v;
    }
    __shared__ float rs[256], rq[256];
    rs[tid] = s; rq[tid] = sq;
    __syncthreads();
    for (int st = 128; st > 0; st >>= 1) {
        if (tid < st) { rs[tid] += rs[tid + st]; rq[tid] += rq[tid + st]; }
        __syncthreads();
    }
    if (tid == 0) {
        float mu  = rs[0] / 32768.0f;
        float var = rq[0] / 32768.0f - mu * mu;
        stats[o]       = mu;
        stats[256 + o] = rsqrtf(var + 1e-5f);
    }
}

// ---------------- Kernel 5: normalize + relu ----------------
__global__ void k_norm(const float* __restrict__ y, const float* __restrict__ stats,
                       const float* __restrict__ gamma, const float* __restrict__ beta,
                       float* __restrict__ out) {
    int i4 = blockIdx.x * 256 + threadIdx.x;       // float4 index
    if (i4 >= (2 * CO * HW) / 4) return;
    int o = (i4 >> 12) & 255;
    float g  = gamma[o] * stats[256 + o];
    float bt = beta[o] - stats[o] * g;
    float4 v = ((const float4*)y)[i4];
    float4 r;
    r.x = fmaxf(fmaf(v.x, g, bt), 0.0f);
    r.y = fmaxf(fmaf(v.y, g, bt), 0.0f);
    r.z = fmaxf(fmaf(v.z, g, bt), 0.0f);
    r.w = fmaxf(fmaf(v.w, g, bt), 0.0f);
    ((float4*)out)[i4] = r;
}

extern "C" void kernel_launch(void* const* d_in, const int* in_sizes, int n_in,
                              void* d_out, int out_size, void* d_ws, size_t ws_size,
                              hipStream_t stream) {
    const float* x      = (const float*)d_in[0];
    const float* w_off  = (const float*)d_in[1];
    const float* b_off  = (const float*)d_in[2];
    const float* weight = (const float*)d_in[3];
    const float* bias   = (const float*)d_in[4];
    const float* gamma  = (const float*)d_in[5];
    const float* beta   = (const float*)d_in[6];
    float* out = (float*)d_out;

    float* ws  = (float*)d_ws;
    float* om  = ws;                       // 2*27*16384      = 884736
    float* wt  = om + 884736;              // 256*9*256       = 589824
    float* yb  = wt + 589824;              // 2*256*16384     = 8388608
    float* st  = yb + 8388608;             // 512

    // 1: weight transpose
    k_wt<<<(Cc * KK * CO + 255) / 256, 256, 0, stream>>>(weight, wt);
    // 2: offset conv
    k_offconv<<<dim3(256, 27), 128, 0, stream>>>(x, w_off, b_off, om);
    // 3: fused gather + GEMM
    k_main<<<1024, 256, 0, stream>>>(x, om, wt, bias, yb);
    // 4: stats
    k_stats<<<CO, 256, 0, stream>>>(yb, st);
    // 5: normalize + relu
    k_norm<<<(2 * CO * HW / 4 + 255) / 256, 256, 0, stream>>>(yb, st, gamma, beta, out);
}

// Round 2
// 848.625 us; speedup vs baseline: 1.4795x; 1.4795x over previous
//
#include <hip/hip_runtime.h>
#include <math.h>

#define HW   16384
#define Hh   128
#define Ww   128
#define Cc   256
#define CO   256
#define KK   9

// ---------------- Kernel 1: main weight transpose (o,c,k) -> (c*9+k, o) ----------------
__global__ void k_wt(const float* __restrict__ w, float* __restrict__ wt) {
    int idx = blockIdx.x * 256 + threadIdx.x;      // over (c*9+k)*256 + o
    if (idx >= Cc * KK * CO) return;
    int o  = idx & 255;
    int ck = idx >> 8;                             // c*9+k
    int c  = ck / 9;
    int k  = ck - c * 9;
    wt[idx] = w[(o * Cc + c) * 9 + k];
}

// ---------------- Kernel 1b: offset weight transpose (oc,c,t) -> (c*27+oc)*9+t ----------------
__global__ void k_wt2(const float* __restrict__ w, float* __restrict__ wt) {
    int idx = blockIdx.x * 256 + threadIdx.x;      // over 256*27*9 = 62208
    if (idx >= Cc * 27 * 9) return;
    int t  = idx % 9;
    int r  = idx / 9;
    int oc = r % 27;
    int c  = r / 27;
    wt[idx] = w[((size_t)oc * Cc + c) * 9 + t];
}

// ---------------- Kernel 2: offset conv 3x3, all 27 ocs per thread ----------------
// grid: 512 = b*256 + h*2 + wh; block 256 = 4 channel-groups x 64 w-lanes.
// Each thread: 64 input channels, 9 x-loads/channel, 243 FMAs/channel.
// Weights are read at wave-uniform addresses ([c][27][9] layout) -> s_load.
__global__ __launch_bounds__(256) void k_offconv2(const float* __restrict__ x,
                                                  const float* __restrict__ wt_off,
                                                  const float* __restrict__ bof,
                                                  float* __restrict__ om) {
    const int tid  = threadIdx.x;
    const int wl   = tid & 63;
    const int g    = tid >> 6;                 // channel group 0..3
    const int bidx = blockIdx.x;               // b*256 + h*2 + wh
    const int wh   = bidx & 1;
    const int h    = (bidx >> 1) & 127;
    const int b    = bidx >> 8;
    const int w    = wh * 64 + wl;

    float a[27];
    #pragma unroll
    for (int i = 0; i < 27; ++i) a[i] = 0.0f;

    const float* xb = x + (size_t)b * Cc * HW;
    const int c0 = g * 64;

    for (int c = c0; c < c0 + 64; ++c) {
        const float* xc = xb + (size_t)c * HW;
        float xv[9];
        #pragma unroll
        for (int dh = 0; dh < 3; ++dh) {
            int hy = h + dh - 1;
            bool vy = (hy >= 0) && (hy <= 127);
            const float* xr = xc + (vy ? hy : 0) * 128;
            #pragma unroll
            for (int dw = 0; dw < 3; ++dw) {
                int wx = w + dw - 1;
                bool v = vy && (wx >= 0) && (wx <= 127);
                int wxc = min(max(wx, 0), 127);
                xv[dh * 3 + dw] = v ? xr[wxc] : 0.0f;
            }
        }
        const float* wc = wt_off + (size_t)c * 243;   // wave-uniform -> scalar loads
        #pragma unroll
        for (int oc = 0; oc < 27; ++oc) {
            #pragma unroll
            for (int t = 0; t < 9; ++t)
                a[oc] = fmaf(xv[t], wc[oc * 9 + t], a[oc]);
        }
    }

    // reduce the 4 channel-group partials
    __shared__ float red[4][27][64];
    #pragma unroll
    for (int i = 0; i < 27; ++i) red[g][i][wl] = a[i];
    __syncthreads();

    for (int idx = tid; idx < 27 * 64; idx += 256) {
        int oc = idx >> 6;
        int ww = idx & 63;
        float v = red[0][oc][ww] + red[1][oc][ww] + red[2][oc][ww] + red[3][oc][ww] + bof[oc];
        om[((size_t)b * 27 + oc) * HW + h * 128 + wh * 64 + ww] = v;
    }
}

// ---------------- Kernel 3: fused deform-gather + GEMM ----------------
// block: 256 threads; each block: one b, one h row, 32 w positions, all 256 o.
// thread: to = tid&63 -> 4 consecutive o; tj = tid>>6 -> 8 consecutive j.
__global__ __launch_bounds__(256) void k_main(const float* __restrict__ x,
                                              const float* __restrict__ om,
                                              const float* __restrict__ wt,
                                              const float* __restrict__ bias,
                                              float* __restrict__ y) {
    __shared__ float s_lds[32][32];
    __shared__ float w_lds[32][256];
    __shared__ int   c_off[32][4];
    __shared__ float c_w[32][4];

    const int tid  = threadIdx.x;
    const int bidx = blockIdx.x;                 // b*512 + h*4 + wt4
    const int wt4  = bidx & 3;
    const int h    = (bidx >> 2) & 127;
    const int b    = bidx >> 9;
    const int w0   = wt4 * 32;

    const int to = tid & 63;
    const int tj = tid >> 6;

    float acc[4][8];
    #pragma unroll
    for (int oi = 0; oi < 4; ++oi)
        #pragma unroll
        for (int ji = 0; ji < 8; ++ji) acc[oi][ji] = 0.0f;

    const float* xb = x + (size_t)b * Cc * HW;
    const size_t ombase = (size_t)b * 27 * HW;

    for (int k = 0; k < KK; ++k) {
        // ---- stage bilinear coords + weights (incl. sigmoid mask) for 32 positions ----
        if (tid < 32) {
            int j  = tid;
            int hw = h * 128 + w0 + j;
            float oy = om[ombase + (size_t)k * HW + hw];
            float ox = om[ombase + (size_t)(9 + k) * HW + hw];
            float mv = om[ombase + (size_t)(18 + k) * HW + hw];
            mv = 1.0f / (1.0f + expf(-mv));
            float py = (float)h - 1.0f + (float)(k / 3) + oy;
            float px = (float)(w0 + j) - 1.0f + (float)(k % 3) + ox;
            float y0f = floorf(py), x0f = floorf(px);
            float wy = py - y0f, wx = px - x0f;
            int iy = (int)y0f, ix = (int)x0f;
            float ww[4] = {(1.0f - wy) * (1.0f - wx), (1.0f - wy) * wx,
                           wy * (1.0f - wx),          wy * wx};
            const int dy[4] = {0, 0, 1, 1};
            const int dx[4] = {0, 1, 0, 1};
            #pragma unroll
            for (int r = 0; r < 4; ++r) {
                int yy = iy + dy[r], xx = ix + dx[r];
                bool v = (yy >= 0) && (yy <= 127) && (xx >= 0) && (xx <= 127);
                int yc = min(max(yy, 0), 127);
                int xc = min(max(xx, 0), 127);
                c_off[j][r] = yc * 128 + xc;
                c_w[j][r]   = v ? ww[r] * mv : 0.0f;
            }
        }
        __syncthreads();

        for (int c0 = 0; c0 < Cc; c0 += 32) {
            // ---- stage W tile: w_lds[c][o] for c in chunk, all o ----
            const float* wsrc = wt + ((size_t)c0 * 9 + k) * 256 + tid;
            #pragma unroll
            for (int c = 0; c < 32; ++c)
                w_lds[c][tid] = wsrc[(size_t)c * 9 * 256];

            // ---- stage S tile: gather s_lds[c][j] ----
            {
                int j     = tid & 31;
                int cbase = tid >> 5;
                #pragma unroll
                for (int i = 0; i < 4; ++i) {
                    int c = cbase + 8 * i;
                    const float* xc = xb + (size_t)(c0 + c) * HW;
                    float v = c_w[j][0] * xc[c_off[j][0]]
                            + c_w[j][1] * xc[c_off[j][1]]
                            + c_w[j][2] * xc[c_off[j][2]]
                            + c_w[j][3] * xc[c_off[j][3]];
                    s_lds[c][j] = v;
                }
            }
            __syncthreads();

            // ---- FMA: 4o x 8j register tile ----
            #pragma unroll 4
            for (int c = 0; c < 32; ++c) {
                const float4 wv = *(const float4*)&w_lds[c][to * 4];
                const float4 sa = *(const float4*)&s_lds[c][tj * 8];
                const float4 sb = *(const float4*)&s_lds[c][tj * 8 + 4];
                float wvv[4] = {wv.x, wv.y, wv.z, wv.w};
                float sv[8]  = {sa.x, sa.y, sa.z, sa.w, sb.x, sb.y, sb.z, sb.w};
                #pragma unroll
                for (int oi = 0; oi < 4; ++oi)
                    #pragma unroll
                    for (int ji = 0; ji < 8; ++ji)
                        acc[oi][ji] = fmaf(wvv[oi], sv[ji], acc[oi][ji]);
            }
            __syncthreads();
        }
    }

    // ---- epilogue: add bias, write y ----
    #pragma unroll
    for (int oi = 0; oi < 4; ++oi) {
        int o = to * 4 + oi;
        float bb = bias[o];
        float* yo = y + ((size_t)b * CO + o) * HW + h * 128 + w0 + tj * 8;
        float4 v0 = make_float4(acc[oi][0] + bb, acc[oi][1] + bb, acc[oi][2] + bb, acc[oi][3] + bb);
        float4 v1 = make_float4(acc[oi][4] + bb, acc[oi][5] + bb, acc[oi][6] + bb, acc[oi][7] + bb);
        *(float4*)&yo[0] = v0;
        *(float4*)&yo[4] = v1;
    }
}

// ---------------- Kernel 4: per-channel mean/var ----------------
__global__ void k_stats(const float* __restrict__ y, float* __restrict__ stats) {
    int o   = blockIdx.x;
    int tid = threadIdx.x;
    float s = 0.0f, sq = 0.0f;
    const float* y0 = y + (size_t)o * HW;
    const float* y1 = y + (size_t)(CO + o) * HW;
    for (int i = tid; i < HW; i += 256) {
        float v = y0[i]; s += v; sq += v * v;
        v = y1[i];       s += v; sq += v * v;
    }
    __shared__ float rs[256], rq[256];
    rs[tid] = s; rq[tid] = sq;
    __syncthreads();
    for (int st = 128; st > 0; st >>= 1) {
        if (tid < st) { rs[tid] += rs[tid + st]; rq[tid] += rq[tid + st]; }
        __syncthreads();
    }
    if (tid == 0) {
        float mu  = rs[0] / 32768.0f;
        float var = rq[0] / 32768.0f - mu * mu;
        stats[o]       = mu;
        stats[256 + o] = rsqrtf(var + 1e-5f);
    }
}

// ---------------- Kernel 5: normalize + relu ----------------
__global__ void k_norm(const float* __restrict__ y, const float* __restrict__ stats,
                       const float* __restrict__ gamma, const float* __restrict__ beta,
                       float* __restrict__ out) {
    int i4 = blockIdx.x * 256 + threadIdx.x;       // float4 index
    if (i4 >= (2 * CO * HW) / 4) return;
    int o = (i4 >> 12) & 255;
    float g  = gamma[o] * stats[256 + o];
    float bt = beta[o] - stats[o] * g;
    float4 v = ((const float4*)y)[i4];
    float4 r;
    r.x = fmaxf(fmaf(v.x, g, bt), 0.0f);
    r.y = fmaxf(fmaf(v.y, g, bt), 0.0f);
    r.z = fmaxf(fmaf(v.z, g, bt), 0.0f);
    r.w = fmaxf(fmaf(v.w, g, bt), 0.0f);
    ((float4*)out)[i4] = r;
}

extern "C" void kernel_launch(void* const* d_in, const int* in_sizes, int n_in,
                              void* d_out, int out_size, void* d_ws, size_t ws_size,
                              hipStream_t stream) {
    const float* x      = (const float*)d_in[0];
    const float* w_off  = (const float*)d_in[1];
    const float* b_off  = (const float*)d_in[2];
    const float* weight = (const float*)d_in[3];
    const float* bias   = (const float*)d_in[4];
    const float* gamma  = (const float*)d_in[5];
    const float* beta   = (const float*)d_in[6];
    float* out = (float*)d_out;

    float* ws   = (float*)d_ws;
    float* om   = ws;                       // 2*27*16384      = 884736
    float* wt   = om + 884736;              // 256*9*256       = 589824
    float* yb   = wt + 589824;              // 2*256*16384     = 8388608
    float* st   = yb + 8388608;             // 512
    float* wto  = st + 512;                 // 256*27*9        = 62208

    // 1: weight transposes
    k_wt<<<(Cc * KK * CO + 255) / 256, 256, 0, stream>>>(weight, wt);
    k_wt2<<<(Cc * 27 * 9 + 255) / 256, 256, 0, stream>>>(w_off, wto);
    // 2: offset conv (27 ocs fused per thread)
    k_offconv2<<<512, 256, 0, stream>>>(x, wto, b_off, om);
    // 3: fused gather + GEMM
    k_main<<<1024, 256, 0, stream>>>(x, om, wt, bias, yb);
    // 4: stats
    k_stats<<<CO, 256, 0, stream>>>(yb, st);
    // 5: normalize + relu
    k_norm<<<(2 * CO * HW / 4 + 255) / 256, 256, 0, stream>>>(yb, st, gamma, beta, out);
}

// Round 3
// 595.834 us; speedup vs baseline: 2.1073x; 1.4243x over previous
//
#include <hip/hip_runtime.h>
#include <math.h>

#define HW 16384
#define Cc 256
#define CO 256

typedef unsigned short u16;
typedef unsigned int   u32;
typedef __attribute__((ext_vector_type(8))) short bf16x8;
typedef __attribute__((ext_vector_type(4))) float f32x4;

__device__ __forceinline__ u16 f2bf(float f) {
    u32 u = __float_as_uint(f);
    u32 r = (u + 0x7fffu + ((u >> 16) & 1u)) >> 16;
    return (u16)r;
}

// ---------------- Kernel 1b: offset weight transpose (oc,c,t) -> (c*27+oc)*9+t ----------------
__global__ void k_wt2(const float* __restrict__ w, float* __restrict__ wt) {
    int idx = blockIdx.x * 256 + threadIdx.x;
    if (idx >= Cc * 27 * 9) return;
    int t  = idx % 9;
    int r  = idx / 9;
    int oc = r % 27;
    int c  = r / 27;
    wt[idx] = w[((size_t)oc * Cc + c) * 9 + t];
}

// ---------------- Kernel 1c: main weight -> bf16 fragment-order ----------------
// wfr element id = ((otile*72 + k32)*64 + lane)*8 + i  holds  W[o][K] with
// o = otile*16 + (lane&15), K = k32*32 + (lane>>4)*8 + i, K = ktap*256 + c.
__global__ void k_wbf(const float* __restrict__ w, u16* __restrict__ wfr) {
    int id = blockIdx.x * 256 + threadIdx.x;
    if (id >= 589824) return;
    int i    = id & 7;
    int lane = (id >> 3) & 63;
    int fb   = id >> 9;
    int k32  = fb % 72;
    int ot   = fb / 72;
    int o  = ot * 16 + (lane & 15);
    int K  = k32 * 32 + (lane >> 4) * 8 + i;
    int kt = K >> 8;
    int c  = K & 255;
    wfr[id] = f2bf(w[((size_t)o * 256 + c) * 9 + kt]);
}

// ---------------- Kernel 2: offset conv 3x3, all 27 ocs per thread ----------------
__global__ __launch_bounds__(256) void k_offconv2(const float* __restrict__ x,
                                                  const float* __restrict__ wt_off,
                                                  const float* __restrict__ bof,
                                                  float* __restrict__ om) {
    const int tid  = threadIdx.x;
    const int wl   = tid & 63;
    const int g    = tid >> 6;
    const int bidx = blockIdx.x;
    const int wh   = bidx & 1;
    const int h    = (bidx >> 1) & 127;
    const int b    = bidx >> 8;
    const int w    = wh * 64 + wl;

    float a[27];
    #pragma unroll
    for (int i = 0; i < 27; ++i) a[i] = 0.0f;

    const float* xb = x + (size_t)b * Cc * HW;
    const int c0 = g * 64;

    for (int c = c0; c < c0 + 64; ++c) {
        const float* xc = xb + (size_t)c * HW;
        float xv[9];
        #pragma unroll
        for (int dh = 0; dh < 3; ++dh) {
            int hy = h + dh - 1;
            bool vy = (hy >= 0) && (hy <= 127);
            const float* xr = xc + (vy ? hy : 0) * 128;
            #pragma unroll
            for (int dw = 0; dw < 3; ++dw) {
                int wx = w + dw - 1;
                bool v = vy && (wx >= 0) && (wx <= 127);
                int wxc = min(max(wx, 0), 127);
                xv[dh * 3 + dw] = v ? xr[wxc] : 0.0f;
            }
        }
        const float* wc = wt_off + (size_t)c * 243;
        #pragma unroll
        for (int oc = 0; oc < 27; ++oc) {
            #pragma unroll
            for (int t = 0; t < 9; ++t)
                a[oc] = fmaf(xv[t], wc[oc * 9 + t], a[oc]);
        }
    }

    __shared__ float red[4][27][64];
    #pragma unroll
    for (int i = 0; i < 27; ++i) red[g][i][wl] = a[i];
    __syncthreads();

    for (int idx = tid; idx < 27 * 64; idx += 256) {
        int oc = idx >> 6;
        int ww = idx & 63;
        float v = red[0][oc][ww] + red[1][oc][ww] + red[2][oc][ww] + red[3][oc][ww] + bof[oc];
        om[((size_t)b * 27 + oc) * HW + h * 128 + wh * 64 + ww] = v;
    }
}

// ---------------- Kernel 3a: deform gather -> bf16 S, pre-swizzled layout ----------------
// Chunk = 3 taps. Sc row (per pos p): 1536 B = 12 x 128B blocks (K' = kt*256+c, 64 K per block).
// Stored byte-in-block = ((K'&63)*2) ^ ((p&7)<<4)  (16B-granular XOR swizzle).
__global__ __launch_bounds__(256) void k_gather(const float* __restrict__ x,
                                                const float* __restrict__ om,
                                                u16* __restrict__ Sc, int kbase) {
    __shared__ int4   soff[128];
    __shared__ float4 swt[128];
    const int tid = threadIdx.x;
    const int bid = blockIdx.x;               // 768 = b*384 + kt*128 + h
    const int h  = bid & 127;
    const int g3 = bid >> 7;                  // 0..5
    const int kt = g3 % 3;
    const int b  = g3 / 3;
    const int k  = kbase + kt;

    if (tid < 128) {
        int j  = tid;
        int hw = h * 128 + j;
        const size_t ob = (size_t)b * 27 * HW;
        float oy = om[ob + (size_t)k * HW + hw];
        float ox = om[ob + (size_t)(9 + k) * HW + hw];
        float mv = om[ob + (size_t)(18 + k) * HW + hw];
        mv = 1.0f / (1.0f + expf(-mv));
        float py = (float)h - 1.0f + (float)(k / 3) + oy;
        float px = (float)j - 1.0f + (float)(k % 3) + ox;
        float y0f = floorf(py), x0f = floorf(px);
        float wy = py - y0f, wx = px - x0f;
        int iy = (int)y0f, ix = (int)x0f;
        float w4[4] = {(1.0f - wy) * (1.0f - wx), (1.0f - wy) * wx,
                       wy * (1.0f - wx),          wy * wx};
        const int dy[4] = {0, 0, 1, 1};
        const int dx[4] = {0, 1, 0, 1};
        int   ofs[4];
        float cwv[4];
        #pragma unroll
        for (int r = 0; r < 4; ++r) {
            int yy = iy + dy[r], xx = ix + dx[r];
            bool v = (yy >= 0) && (yy <= 127) && (xx >= 0) && (xx <= 127);
            int yc = min(max(yy, 0), 127);
            int xc = min(max(xx, 0), 127);
            ofs[r] = yc * 128 + xc;
            cwv[r] = v ? w4[r] * mv : 0.0f;
        }
        soff[j] = make_int4(ofs[0], ofs[1], ofs[2], ofs[3]);
        swt[j]  = make_float4(cwv[0], cwv[1], cwv[2], cwv[3]);
    }
    __syncthreads();

    const int j     = (tid & 63) | (((tid >> 6) & 1) << 6);
    const int obase = tid >> 7;                 // 0..1
    const int4   off = soff[j];
    const float4 cw  = swt[j];
    const int p = b * HW + h * 128 + j;
    char* ScC = (char*)Sc;
    const size_t rowb = (size_t)p * 1536;
    const u32 swz = (u32)((p & 7) << 4);

    for (int i = 0; i < 16; ++i) {
        int octet = obase + 2 * i;              // 0..31
        int c0 = octet * 8;
        float v[8];
        #pragma unroll
        for (int ci = 0; ci < 8; ++ci) {
            const float* xc = x + (((size_t)b * 256 + (c0 + ci)) << 14);
            v[ci] = cw.x * xc[off.x] + cw.y * xc[off.y]
                  + cw.z * xc[off.z] + cw.w * xc[off.w];
        }
        u32 o4[4];
        #pragma unroll
        for (int q = 0; q < 4; ++q)
            o4[q] = (u32)f2bf(v[2 * q]) | ((u32)f2bf(v[2 * q + 1]) << 16);
        int Kp = kt * 256 + c0;
        size_t byte = rowb + (size_t)((Kp >> 6) << 7) + (u32)((u32)((Kp & 63) * 2) ^ swz);
        *(uint4*)(ScC + byte) = make_uint4(o4[0], o4[1], o4[2], o4[3]);
    }
}

// ---------------- Kernel 3b: bf16 MFMA GEMM over one K-chunk (768) ----------------
// Grid 512 pos-tiles (BN=64); block 256 = 4 waves; wave = 64 o x 64 pos.
// A-frags direct from global (fragment-order wfr, L2-hot); B-tile LDS double-buffered.
__global__ __launch_bounds__(256) void k_gemm(const u16* __restrict__ Sc,
                                              const u16* __restrict__ wfr,
                                              const float* __restrict__ bias,
                                              float* __restrict__ y, int chunk) {
    __shared__ u16 Blds[2][4096];               // 2 x 8 KB
    const int tid  = threadIdx.x;
    const int wid  = tid >> 6;
    const int lane = tid & 63;
    const int p0   = blockIdx.x * 64;
    const char* ScC = (const char*)Sc;

    f32x4 acc[4][4];
    #pragma unroll
    for (int m = 0; m < 4; ++m)
        #pragma unroll
        for (int n = 0; n < 4; ++n) acc[m][n] = (f32x4)0.0f;

    const int lg = lane >> 4;                   // k-group 0..3
    const int lr = lane & 15;

    // ---- prologue: stage s=0, load a-frags s=0 ----
    bf16x8 af[2][4];
    {
        size_t sb = (size_t)(p0 + (tid >> 3)) * 1536 + (size_t)(tid & 7) * 16;
        uint4 g0 = *(const uint4*)(ScC + sb);
        uint4 g1 = *(const uint4*)(ScC + sb + 32 * 1536);
        *(uint4*)((char*)&Blds[0][0] + tid * 16)        = g0;
        *(uint4*)((char*)&Blds[0][0] + tid * 16 + 4096) = g1;
        int k32g = chunk * 24;
        #pragma unroll
        for (int kk = 0; kk < 2; ++kk)
            #pragma unroll
            for (int m = 0; m < 4; ++m)
                af[kk][m] = *(const bf16x8*)(wfr +
                    ((size_t)((wid * 4 + m) * 72 + k32g + kk) << 9) + (size_t)lane * 8);
    }
    __syncthreads();

    int cur = 0;
    for (int s = 0; s < 12; ++s) {
        const int nxt = cur ^ 1;
        uint4 g0, g1;
        bf16x8 afn[2][4];
        if (s < 11) {
            size_t sb = (size_t)(p0 + (tid >> 3)) * 1536 + (size_t)(s + 1) * 128 + (size_t)(tid & 7) * 16;
            g0 = *(const uint4*)(ScC + sb);
            g1 = *(const uint4*)(ScC + sb + 32 * 1536);
            int k32g = chunk * 24 + (s + 1) * 2;
            #pragma unroll
            for (int kk = 0; kk < 2; ++kk)
                #pragma unroll
                for (int m = 0; m < 4; ++m)
                    afn[kk][m] = *(const bf16x8*)(wfr +
                        ((size_t)((wid * 4 + m) * 72 + k32g + kk) << 9) + (size_t)lane * 8);
        }

        const char* bb = (const char*)&Blds[cur][0];
        #pragma unroll
        for (int kk = 0; kk < 2; ++kk) {
            bf16x8 bfv[4];
            #pragma unroll
            for (int n = 0; n < 4; ++n) {
                int row  = n * 16 + lr;
                int boff = row * 128 + (((kk * 64 + lg * 16)) ^ ((row & 7) << 4));
                bfv[n] = *(const bf16x8*)(bb + boff);
            }
            #pragma unroll
            for (int m = 0; m < 4; ++m)
                #pragma unroll
                for (int n = 0; n < 4; ++n)
                    acc[m][n] = __builtin_amdgcn_mfma_f32_16x16x32_bf16(af[kk][m], bfv[n], acc[m][n], 0, 0, 0);
        }

        if (s < 11) {
            *(uint4*)((char*)&Blds[nxt][0] + tid * 16)        = g0;
            *(uint4*)((char*)&Blds[nxt][0] + tid * 16 + 4096) = g1;
            #pragma unroll
            for (int kk = 0; kk < 2; ++kk)
                #pragma unroll
                for (int m = 0; m < 4; ++m)
                    af[kk][m] = afn[kk][m];
        }
        __syncthreads();
        cur = nxt;
    }

    // ---- epilogue: accumulate into y ----
    const int bb_  = p0 >> 14;
    const int hw0  = (p0 & 16383) + lr;
    #pragma unroll
    for (int m = 0; m < 4; ++m) {
        #pragma unroll
        for (int j = 0; j < 4; ++j) {
            int o = wid * 64 + m * 16 + lg * 4 + j;
            float bv = bias[o];
            float* ya = y + ((size_t)bb_ * 256 + o) * HW + hw0;
            #pragma unroll
            for (int n = 0; n < 4; ++n) {
                float val = acc[m][n][j];
                if (chunk == 0) val += bv;
                else            val += ya[n * 16];
                ya[n * 16] = val;
            }
        }
    }
}

// ---------------- Kernel 4: per-channel mean/var ----------------
__global__ void k_stats(const float* __restrict__ y, float* __restrict__ stats) {
    int o   = blockIdx.x;
    int tid = threadIdx.x;
    float s = 0.0f, sq = 0.0f;
    const float* y0 = y + (size_t)o * HW;
    const float* y1 = y + (size_t)(CO + o) * HW;
    for (int i = tid; i < HW; i += 256) {
        float v = y0[i]; s += v; sq += v * v;
        v = y1[i];       s += v; sq += v * v;
    }
    __shared__ float rs[256], rq[256];
    rs[tid] = s; rq[tid] = sq;
    __syncthreads();
    for (int st = 128; st > 0; st >>= 1) {
        if (tid < st) { rs[tid] += rs[tid + st]; rq[tid] += rq[tid + st]; }
        __syncthreads();
    }
    if (tid == 0) {
        float mu  = rs[0] / 32768.0f;
        float var = rq[0] / 32768.0f - mu * mu;
        stats[o]       = mu;
        stats[256 + o] = rsqrtf(var + 1e-5f);
    }
}

// ---------------- Kernel 5: normalize + relu ----------------
__global__ void k_norm(const float* __restrict__ y, const float* __restrict__ stats,
                       const float* __restrict__ gamma, const float* __restrict__ beta,
                       float* __restrict__ out) {
    int i4 = blockIdx.x * 256 + threadIdx.x;
    if (i4 >= (2 * CO * HW) / 4) return;
    int o = (i4 >> 12) & 255;
    float g  = gamma[o] * stats[256 + o];
    float bt = beta[o] - stats[o] * g;
    float4 v = ((const float4*)y)[i4];
    float4 r;
    r.x = fmaxf(fmaf(v.x, g, bt), 0.0f);
    r.y = fmaxf(fmaf(v.y, g, bt), 0.0f);
    r.z = fmaxf(fmaf(v.z, g, bt), 0.0f);
    r.w = fmaxf(fmaf(v.w, g, bt), 0.0f);
    ((float4*)out)[i4] = r;
}

extern "C" void kernel_launch(void* const* d_in, const int* in_sizes, int n_in,
                              void* d_out, int out_size, void* d_ws, size_t ws_size,
                              hipStream_t stream) {
    const float* x      = (const float*)d_in[0];
    const float* w_off  = (const float*)d_in[1];
    const float* b_off  = (const float*)d_in[2];
    const float* weight = (const float*)d_in[3];
    const float* bias   = (const float*)d_in[4];
    const float* gamma  = (const float*)d_in[5];
    const float* beta   = (const float*)d_in[6];
    float* out = (float*)d_out;

    float* ws  = (float*)d_ws;
    float* om  = ws;                        // 884736 f
    float* wto = om + 884736;               // 62208 f
    float* st  = wto + 62208;               // 512 f
    float* yb  = st + 512;                  // 8388608 f
    u16*   wfr = (u16*)(yb + 8388608);      // 589824 u16 (294912 f)
    u16*   Sc  = (u16*)((float*)(void*)wfr + 294912);  // 25165824 u16 (12582912 f) ~50.3 MB

    k_wbf<<<2304, 256, 0, stream>>>(weight, wfr);
    k_wt2<<<(Cc * 27 * 9 + 255) / 256, 256, 0, stream>>>(w_off, wto);
    k_offconv2<<<512, 256, 0, stream>>>(x, wto, b_off, om);

    for (int g = 0; g < 3; ++g) {
        k_gather<<<768, 256, 0, stream>>>(x, om, Sc, 3 * g);
        k_gemm<<<512, 256, 0, stream>>>(Sc, wfr, bias, yb, g);
    }

    k_stats<<<CO, 256, 0, stream>>>(yb, st);
    k_norm<<<(2 * CO * HW / 4 + 255) / 256, 256, 0, stream>>>(yb, st, gamma, beta, out);
}

// Round 4
// 385.558 us; speedup vs baseline: 3.2565x; 1.5454x over previous
//
#include <hip/hip_runtime.h>
#include <math.h>

#define HW 16384
#define Cc 256
#define CO 256

typedef unsigned short u16;
typedef unsigned int   u32;
typedef __attribute__((ext_vector_type(8))) short bf16x8;
typedef __attribute__((ext_vector_type(4))) float f32x4;

__device__ __forceinline__ u16 f2bf(float f) {
    u32 u = __float_as_uint(f);
    u32 r = (u + 0x7fffu + ((u >> 16) & 1u)) >> 16;
    return (u16)r;
}

// ---------------- Kernel 1c: main weight -> bf16 fragment-order ----------------
__global__ void k_wbf(const float* __restrict__ w, u16* __restrict__ wfr) {
    int id = blockIdx.x * 256 + threadIdx.x;
    if (id >= 589824) return;
    int i    = id & 7;
    int lane = (id >> 3) & 63;
    int fb   = id >> 9;
    int k32  = fb % 72;
    int ot   = fb / 72;
    int o  = ot * 16 + (lane & 15);
    int K  = k32 * 32 + (lane >> 4) * 8 + i;
    int kt = K >> 8;
    int c  = K & 255;
    wfr[id] = f2bf(w[((size_t)o * 256 + c) * 9 + kt]);
}

// ---------------- Kernel 1d: offset weight -> bf16 fragment-order (M 27->32 pad) ----------------
// K = t*256 + c (tap-major). wofr id = ((mt*72 + k32)*64 + lane)*8 + i
__global__ void k_wof_fr(const float* __restrict__ w, u16* __restrict__ wofr) {
    int id = blockIdx.x * 256 + threadIdx.x;
    if (id >= 73728) return;
    int i    = id & 7;
    int lane = (id >> 3) & 63;
    int fb   = id >> 9;
    int k32  = fb % 72;
    int mt   = fb / 72;
    int o  = mt * 16 + (lane & 15);
    int K  = k32 * 32 + (lane >> 4) * 8 + i;
    int t  = K >> 8;
    int c  = K & 255;
    float v = (o < 27) ? w[((size_t)o * 256 + c) * 9 + t] : 0.0f;
    wofr[id] = f2bf(v);
}

// ---------------- Kernel 1e: x -> Xt[b][hw][c] bf16 ----------------
// block: 256 thr = 64 hw-lanes x 4 channel-groups; coalesced reads, 16B writes.
__global__ __launch_bounds__(256) void k_xt(const float* __restrict__ x, u16* __restrict__ Xt) {
    const int tid = threadIdx.x;
    const int bid = blockIdx.x;              // 512 = b*256 + hwblk
    const int hw0 = (bid & 255) * 64;
    const int b   = bid >> 8;
    const int hwl = tid & 63;
    const int cg  = tid >> 6;                // 0..3 -> 64 channels each
    const int hw  = hw0 + hwl;
    const float* xb = x + ((size_t)b << 22);
    u16* dst = Xt + (((size_t)b << 14) + hw) * 256 + cg * 64;
    #pragma unroll
    for (int oct = 0; oct < 8; ++oct) {
        int c0 = cg * 64 + oct * 8;
        u32 pk[4];
        #pragma unroll
        for (int q = 0; q < 4; ++q) {
            float v0 = xb[((size_t)(c0 + 2 * q) << 14) + hw];
            float v1 = xb[((size_t)(c0 + 2 * q + 1) << 14) + hw];
            pk[q] = (u32)f2bf(v0) | ((u32)f2bf(v1) << 16);
        }
        *(uint4*)(dst + oct * 8) = make_uint4(pk[0], pk[1], pk[2], pk[3]);
    }
}

// ---------------- Kernel 1f: om init with bias ----------------
__global__ void k_ominit(const float* __restrict__ bof, float* __restrict__ om) {
    int idx = blockIdx.x * 256 + threadIdx.x;
    if (idx >= 2 * 27 * HW) return;
    om[idx] = bof[(idx >> 14) % 27];
}

// ---------------- Kernel 2: offset conv as MFMA implicit GEMM ----------------
// grid 2048 = b*1024 + h*8 + wq*4 + kq; block 256 = 4 waves (n-tiles of 16 pos).
// M=32 (27 padded), K-quarter = 18 k32-blocks, atomicAdd into om.
__global__ __launch_bounds__(256) void k_offmfma(const u16* __restrict__ Xt,
                                                 const u16* __restrict__ wofr,
                                                 float* __restrict__ om) {
    const int tid  = threadIdx.x;
    const int wid  = tid >> 6;
    const int lane = tid & 63;
    const int bid  = blockIdx.x;
    const int kq   = bid & 3;
    const int wq   = (bid >> 2) & 1;
    const int h    = (bid >> 3) & 127;
    const int b    = bid >> 10;

    const int lr = lane & 15;
    const int lg = lane >> 4;
    const int w  = wq * 64 + wid * 16 + lr;

    f32x4 acc0 = (f32x4)0.0f, acc1 = (f32x4)0.0f;
    const u16* XtB = Xt + (((size_t)b << 14) << 8);

    #pragma unroll 3
    for (int k32 = kq * 18; k32 < kq * 18 + 18; ++k32) {
        int t   = k32 >> 3;
        int c32 = k32 & 7;
        int dh  = t / 3 - 1;
        int dw  = t % 3 - 1;
        int hh  = h + dh;
        int ww  = w + dw;
        bool valid = (hh >= 0) && (hh < 128) && (ww >= 0) && (ww < 128);
        int hc = min(max(hh, 0), 127);
        int wc = min(max(ww, 0), 127);
        bf16x8 bv = *(const bf16x8*)(XtB + ((size_t)(hc * 128 + wc) << 8) + c32 * 32 + lg * 8);
        if (!valid) bv = (bf16x8)0;
        bf16x8 a0 = *(const bf16x8*)(wofr + (((size_t)k32 * 64 + lane) << 3));
        bf16x8 a1 = *(const bf16x8*)(wofr + ((((size_t)(72 + k32)) * 64 + lane) << 3));
        acc0 = __builtin_amdgcn_mfma_f32_16x16x32_bf16(a0, bv, acc0, 0, 0, 0);
        acc1 = __builtin_amdgcn_mfma_f32_16x16x32_bf16(a1, bv, acc1, 0, 0, 0);
    }

    float* omb = om + ((size_t)b * 27 << 14) + h * 128 + w;
    #pragma unroll
    for (int j = 0; j < 4; ++j) {
        int o = lg * 4 + j;
        atomicAdd(omb + ((size_t)o << 14), acc0[j]);
        int o1 = 16 + lg * 4 + j;
        if (o1 < 27) atomicAdd(omb + ((size_t)o1 << 14), acc1[j]);
    }
}

// ---------------- Kernel 3a: deform gather -> bf16 S, pre-swizzled layout ----------------
__global__ __launch_bounds__(256) void k_gather(const float* __restrict__ x,
                                                const float* __restrict__ om,
                                                u16* __restrict__ Sc, int kbase) {
    __shared__ int4   soff[128];
    __shared__ float4 swt[128];
    const int tid = threadIdx.x;
    const int bid = blockIdx.x;               // 768 = b*384 + kt*128 + h
    const int h  = bid & 127;
    const int g3 = bid >> 7;
    const int kt = g3 % 3;
    const int b  = g3 / 3;
    const int k  = kbase + kt;

    if (tid < 128) {
        int j  = tid;
        int hw = h * 128 + j;
        const size_t ob = (size_t)b * 27 * HW;
        float oy = om[ob + (size_t)k * HW + hw];
        float ox = om[ob + (size_t)(9 + k) * HW + hw];
        float mv = om[ob + (size_t)(18 + k) * HW + hw];
        mv = 1.0f / (1.0f + expf(-mv));
        float py = (float)h - 1.0f + (float)(k / 3) + oy;
        float px = (float)j - 1.0f + (float)(k % 3) + ox;
        float y0f = floorf(py), x0f = floorf(px);
        float wy = py - y0f, wx = px - x0f;
        int iy = (int)y0f, ix = (int)x0f;
        float w4[4] = {(1.0f - wy) * (1.0f - wx), (1.0f - wy) * wx,
                       wy * (1.0f - wx),          wy * wx};
        const int dy[4] = {0, 0, 1, 1};
        const int dx[4] = {0, 1, 0, 1};
        int   ofs[4];
        float cwv[4];
        #pragma unroll
        for (int r = 0; r < 4; ++r) {
            int yy = iy + dy[r], xx = ix + dx[r];
            bool v = (yy >= 0) && (yy <= 127) && (xx >= 0) && (xx <= 127);
            int yc = min(max(yy, 0), 127);
            int xc = min(max(xx, 0), 127);
            ofs[r] = yc * 128 + xc;
            cwv[r] = v ? w4[r] * mv : 0.0f;
        }
        soff[j] = make_int4(ofs[0], ofs[1], ofs[2], ofs[3]);
        swt[j]  = make_float4(cwv[0], cwv[1], cwv[2], cwv[3]);
    }
    __syncthreads();

    const int j     = (tid & 63) | (((tid >> 6) & 1) << 6);
    const int obase = tid >> 7;
    const int4   off = soff[j];
    const float4 cw  = swt[j];
    const int p = b * HW + h * 128 + j;
    char* ScC = (char*)Sc;
    const size_t rowb = (size_t)p * 1536;
    const u32 swz = (u32)((p & 7) << 4);

    for (int i = 0; i < 16; ++i) {
        int octet = obase + 2 * i;
        int c0 = octet * 8;
        float v[8];
        #pragma unroll
        for (int ci = 0; ci < 8; ++ci) {
            const float* xc = x + (((size_t)b * 256 + (c0 + ci)) << 14);
            v[ci] = cw.x * xc[off.x] + cw.y * xc[off.y]
                  + cw.z * xc[off.z] + cw.w * xc[off.w];
        }
        u32 o4[4];
        #pragma unroll
        for (int q = 0; q < 4; ++q)
            o4[q] = (u32)f2bf(v[2 * q]) | ((u32)f2bf(v[2 * q + 1]) << 16);
        int Kp = kt * 256 + c0;
        size_t byte = rowb + (size_t)((Kp >> 6) << 7) + (u32)((u32)((Kp & 63) * 2) ^ swz);
        *(uint4*)(ScC + byte) = make_uint4(o4[0], o4[1], o4[2], o4[3]);
    }
}

// ---------------- Kernel 3b: bf16 MFMA GEMM over one K-chunk (768) ----------------
__global__ __launch_bounds__(256) void k_gemm(const u16* __restrict__ Sc,
                                              const u16* __restrict__ wfr,
                                              const float* __restrict__ bias,
                                              float* __restrict__ y, int chunk) {
    __shared__ u16 Blds[2][4096];
    const int tid  = threadIdx.x;
    const int wid  = tid >> 6;
    const int lane = tid & 63;
    const int p0   = blockIdx.x * 64;
    const char* ScC = (const char*)Sc;

    f32x4 acc[4][4];
    #pragma unroll
    for (int m = 0; m < 4; ++m)
        #pragma unroll
        for (int n = 0; n < 4; ++n) acc[m][n] = (f32x4)0.0f;

    const int lg = lane >> 4;
    const int lr = lane & 15;

    bf16x8 af[2][4];
    {
        size_t sb = (size_t)(p0 + (tid >> 3)) * 1536 + (size_t)(tid & 7) * 16;
        uint4 g0 = *(const uint4*)(ScC + sb);
        uint4 g1 = *(const uint4*)(ScC + sb + 32 * 1536);
        *(uint4*)((char*)&Blds[0][0] + tid * 16)        = g0;
        *(uint4*)((char*)&Blds[0][0] + tid * 16 + 4096) = g1;
        int k32g = chunk * 24;
        #pragma unroll
        for (int kk = 0; kk < 2; ++kk)
            #pragma unroll
            for (int m = 0; m < 4; ++m)
                af[kk][m] = *(const bf16x8*)(wfr +
                    ((size_t)((wid * 4 + m) * 72 + k32g + kk) << 9) + (size_t)lane * 8);
    }
    __syncthreads();

    int cur = 0;
    for (int s = 0; s < 12; ++s) {
        const int nxt = cur ^ 1;
        uint4 g0, g1;
        bf16x8 afn[2][4];
        if (s < 11) {
            size_t sb = (size_t)(p0 + (tid >> 3)) * 1536 + (size_t)(s + 1) * 128 + (size_t)(tid & 7) * 16;
            g0 = *(const uint4*)(ScC + sb);
            g1 = *(const uint4*)(ScC + sb + 32 * 1536);
            int k32g = chunk * 24 + (s + 1) * 2;
            #pragma unroll
            for (int kk = 0; kk < 2; ++kk)
                #pragma unroll
                for (int m = 0; m < 4; ++m)
                    afn[kk][m] = *(const bf16x8*)(wfr +
                        ((size_t)((wid * 4 + m) * 72 + k32g + kk) << 9) + (size_t)lane * 8);
        }

        const char* bb = (const char*)&Blds[cur][0];
        #pragma unroll
        for (int kk = 0; kk < 2; ++kk) {
            bf16x8 bfv[4];
            #pragma unroll
            for (int n = 0; n < 4; ++n) {
                int row  = n * 16 + lr;
                int boff = row * 128 + (((kk * 64 + lg * 16)) ^ ((row & 7) << 4));
                bfv[n] = *(const bf16x8*)(bb + boff);
            }
            #pragma unroll
            for (int m = 0; m < 4; ++m)
                #pragma unroll
                for (int n = 0; n < 4; ++n)
                    acc[m][n] = __builtin_amdgcn_mfma_f32_16x16x32_bf16(af[kk][m], bfv[n], acc[m][n], 0, 0, 0);
        }

        if (s < 11) {
            *(uint4*)((char*)&Blds[nxt][0] + tid * 16)        = g0;
            *(uint4*)((char*)&Blds[nxt][0] + tid * 16 + 4096) = g1;
            #pragma unroll
            for (int kk = 0; kk < 2; ++kk)
                #pragma unroll
                for (int m = 0; m < 4; ++m)
                    af[kk][m] = afn[kk][m];
        }
        __syncthreads();
        cur = nxt;
    }

    const int bb_  = p0 >> 14;
    const int hw0  = (p0 & 16383) + lr;
    #pragma unroll
    for (int m = 0; m < 4; ++m) {
        #pragma unroll
        for (int j = 0; j < 4; ++j) {
            int o = wid * 64 + m * 16 + lg * 4 + j;
            float bv = bias[o];
            float* ya = y + ((size_t)bb_ * 256 + o) * HW + hw0;
            #pragma unroll
            for (int n = 0; n < 4; ++n) {
                float val = acc[m][n][j];
                if (chunk == 0) val += bv;
                else            val += ya[n * 16];
                ya[n * 16] = val;
            }
        }
    }
}

// ---------------- Kernel 4: per-channel mean/var ----------------
__global__ void k_stats(const float* __restrict__ y, float* __restrict__ stats) {
    int o   = blockIdx.x;
    int tid = threadIdx.x;
    float s = 0.0f, sq = 0.0f;
    const float* y0 = y + (size_t)o * HW;
    const float* y1 = y + (size_t)(CO + o) * HW;
    for (int i = tid; i < HW; i += 256) {
        float v = y0[i]; s += v; sq += v * v;
        v = y1[i];       s += v; sq += v * v;
    }
    __shared__ float rs[256], rq[256];
    rs[tid] = s; rq[tid] = sq;
    __syncthreads();
    for (int st = 128; st > 0; st >>= 1) {
        if (tid < st) { rs[tid] += rs[tid + st]; rq[tid] += rq[tid + st]; }
        __syncthreads();
    }
    if (tid == 0) {
        float mu  = rs[0] / 32768.0f;
        float var = rq[0] / 32768.0f - mu * mu;
        stats[o]       = mu;
        stats[256 + o] = rsqrtf(var + 1e-5f);
    }
}

// ---------------- Kernel 5: normalize + relu ----------------
__global__ void k_norm(const float* __restrict__ y, const float* __restrict__ stats,
                       const float* __restrict__ gamma, const float* __restrict__ beta,
                       float* __restrict__ out) {
    int i4 = blockIdx.x * 256 + threadIdx.x;
    if (i4 >= (2 * CO * HW) / 4) return;
    int o = (i4 >> 12) & 255;
    float g  = gamma[o] * stats[256 + o];
    float bt = beta[o] - stats[o] * g;
    float4 v = ((const float4*)y)[i4];
    float4 r;
    r.x = fmaxf(fmaf(v.x, g, bt), 0.0f);
    r.y = fmaxf(fmaf(v.y, g, bt), 0.0f);
    r.z = fmaxf(fmaf(v.z, g, bt), 0.0f);
    r.w = fmaxf(fmaf(v.w, g, bt), 0.0f);
    ((float4*)out)[i4] = r;
}

extern "C" void kernel_launch(void* const* d_in, const int* in_sizes, int n_in,
                              void* d_out, int out_size, void* d_ws, size_t ws_size,
                              hipStream_t stream) {
    const float* x      = (const float*)d_in[0];
    const float* w_off  = (const float*)d_in[1];
    const float* b_off  = (const float*)d_in[2];
    const float* weight = (const float*)d_in[3];
    const float* bias   = (const float*)d_in[4];
    const float* gamma  = (const float*)d_in[5];
    const float* beta   = (const float*)d_in[6];
    float* out = (float*)d_out;

    float* ws   = (float*)d_ws;
    float* om   = ws;                        // 884736 f
    float* st   = om + 884736;               // 512 f
    float* yb   = st + 512;                  // 8388608 f
    u16*   wfr  = (u16*)(yb + 8388608);      // 589824 u16 = 294912 f
    u16*   wofr = (u16*)((float*)(void*)wfr + 294912);   // 73728 u16 = 36864 f
    u16*   Sc   = (u16*)((float*)(void*)wofr + 36864);   // 25165824 u16
    u16*   Xt   = Sc;                        // alias: Xt (16.8 MB) dead before gather writes Sc

    k_wbf<<<2304, 256, 0, stream>>>(weight, wfr);
    k_wof_fr<<<288, 256, 0, stream>>>(w_off, wofr);
    k_xt<<<512, 256, 0, stream>>>(x, Xt);
    k_ominit<<<3456, 256, 0, stream>>>(b_off, om);
    k_offmfma<<<2048, 256, 0, stream>>>(Xt, wofr, om);

    for (int g = 0; g < 3; ++g) {
        k_gather<<<768, 256, 0, stream>>>(x, om, Sc, 3 * g);
        k_gemm<<<512, 256, 0, stream>>>(Sc, wfr, bias, yb, g);
    }

    k_stats<<<CO, 256, 0, stream>>>(yb, st);
    k_norm<<<(2 * CO * HW / 4 + 255) / 256, 256, 0, stream>>>(yb, st, gamma, beta, out);
}

// Round 5
// 151.056 us; speedup vs baseline: 8.3120x; 2.5524x over previous
//
#include <hip/hip_runtime.h>
#include <math.h>

#define HW 16384
#define Cc 256
#define CO 256

typedef unsigned short u16;
typedef unsigned int   u32;
typedef __attribute__((ext_vector_type(8))) short bf16x8;
typedef __attribute__((ext_vector_type(4))) float f32x4;

__device__ __forceinline__ u16 f2bf(float f) {
    u32 u = __float_as_uint(f);
    u32 r = (u + 0x7fffu + ((u >> 16) & 1u)) >> 16;
    return (u16)r;
}
__device__ __forceinline__ float bl(u32 u) { return __uint_as_float(u << 16); }
__device__ __forceinline__ float bh(u32 u) { return __uint_as_float(u & 0xffff0000u); }
__device__ __forceinline__ u32 pkbf(float lo, float hi) {
    u32 ul = __float_as_uint(lo), uh = __float_as_uint(hi);
    u32 rl = (ul + 0x7fffu + ((ul >> 16) & 1u)) >> 16;
    u32 rh = (uh + 0x7fffu + ((uh >> 16) & 1u)) & 0xffff0000u;
    return rl | rh;
}

// ---------------- Kernel 1c: main weight -> bf16 fragment-order ----------------
// wfr id = ((otile*72 + k32)*64 + lane)*8 + i; W[o][K], K = ktap*256 + c.
__global__ void k_wbf(const float* __restrict__ w, u16* __restrict__ wfr) {
    int id = blockIdx.x * 256 + threadIdx.x;
    if (id >= 589824) return;
    int i    = id & 7;
    int lane = (id >> 3) & 63;
    int fb   = id >> 9;
    int k32  = fb % 72;
    int ot   = fb / 72;
    int o  = ot * 16 + (lane & 15);
    int K  = k32 * 32 + (lane >> 4) * 8 + i;
    int kt = K >> 8;
    int c  = K & 255;
    wfr[id] = f2bf(w[((size_t)o * 256 + c) * 9 + kt]);
}

// ---------------- Kernel 1d: offset weight -> bf16 fragment-order (M 27->32 pad) ----------------
__global__ void k_wof_fr(const float* __restrict__ w, u16* __restrict__ wofr) {
    int id = blockIdx.x * 256 + threadIdx.x;
    if (id >= 73728) return;
    int i    = id & 7;
    int lane = (id >> 3) & 63;
    int fb   = id >> 9;
    int k32  = fb % 72;
    int mt   = fb / 72;
    int o  = mt * 16 + (lane & 15);
    int K  = k32 * 32 + (lane >> 4) * 8 + i;
    int t  = K >> 8;
    int c  = K & 255;
    float v = (o < 27) ? w[((size_t)o * 256 + c) * 9 + t] : 0.0f;
    wofr[id] = f2bf(v);
}

// ---------------- Kernel 1e: x -> Xt[b][hw][c] bf16 ----------------
__global__ __launch_bounds__(256) void k_xt(const float* __restrict__ x, u16* __restrict__ Xt) {
    const int tid = threadIdx.x;
    const int bid = blockIdx.x;              // 512 = b*256 + hwblk
    const int hw0 = (bid & 255) * 64;
    const int b   = bid >> 8;
    const int hwl = tid & 63;
    const int cg  = tid >> 6;
    const int hw  = hw0 + hwl;
    const float* xb = x + ((size_t)b << 22);
    u16* dst = Xt + (((size_t)b << 14) + hw) * 256 + cg * 64;
    #pragma unroll
    for (int oct = 0; oct < 8; ++oct) {
        int c0 = cg * 64 + oct * 8;
        u32 pk[4];
        #pragma unroll
        for (int q = 0; q < 4; ++q) {
            float v0 = xb[((size_t)(c0 + 2 * q) << 14) + hw];
            float v1 = xb[((size_t)(c0 + 2 * q + 1) << 14) + hw];
            pk[q] = (u32)f2bf(v0) | ((u32)f2bf(v1) << 16);
        }
        *(uint4*)(dst + oct * 8) = make_uint4(pk[0], pk[1], pk[2], pk[3]);
    }
}

// ---------------- Kernel 1f: om init with bias ----------------
__global__ void k_ominit(const float* __restrict__ bof, float* __restrict__ om) {
    int idx = blockIdx.x * 256 + threadIdx.x;
    if (idx >= 2 * 27 * HW) return;
    om[idx] = bof[(idx >> 14) % 27];
}

// ---------------- Kernel 2: offset conv as MFMA implicit GEMM ----------------
__global__ __launch_bounds__(256) void k_offmfma(const u16* __restrict__ Xt,
                                                 const u16* __restrict__ wofr,
                                                 float* __restrict__ om) {
    const int tid  = threadIdx.x;
    const int wid  = tid >> 6;
    const int lane = tid & 63;
    const int bid  = blockIdx.x;
    const int kq   = bid & 3;
    const int wq   = (bid >> 2) & 1;
    const int h    = (bid >> 3) & 127;
    const int b    = bid >> 10;

    const int lr = lane & 15;
    const int lg = lane >> 4;
    const int w  = wq * 64 + wid * 16 + lr;

    f32x4 acc0 = (f32x4)0.0f, acc1 = (f32x4)0.0f;
    const u16* XtB = Xt + (((size_t)b << 14) << 8);

    #pragma unroll 3
    for (int k32 = kq * 18; k32 < kq * 18 + 18; ++k32) {
        int t   = k32 >> 3;
        int c32 = k32 & 7;
        int dh  = t / 3 - 1;
        int dw  = t % 3 - 1;
        int hh  = h + dh;
        int ww  = w + dw;
        bool valid = (hh >= 0) && (hh < 128) && (ww >= 0) && (ww < 128);
        int hc = min(max(hh, 0), 127);
        int wc = min(max(ww, 0), 127);
        bf16x8 bv = *(const bf16x8*)(XtB + ((size_t)(hc * 128 + wc) << 8) + c32 * 32 + lg * 8);
        if (!valid) bv = (bf16x8)0;
        bf16x8 a0 = *(const bf16x8*)(wofr + (((size_t)k32 * 64 + lane) << 3));
        bf16x8 a1 = *(const bf16x8*)(wofr + ((((size_t)(72 + k32)) * 64 + lane) << 3));
        acc0 = __builtin_amdgcn_mfma_f32_16x16x32_bf16(a0, bv, acc0, 0, 0, 0);
        acc1 = __builtin_amdgcn_mfma_f32_16x16x32_bf16(a1, bv, acc1, 0, 0, 0);
    }

    float* omb = om + ((size_t)b * 27 << 14) + h * 128 + w;
    #pragma unroll
    for (int j = 0; j < 4; ++j) {
        int o = lg * 4 + j;
        atomicAdd(omb + ((size_t)o << 14), acc0[j]);
        int o1 = 16 + lg * 4 + j;
        if (o1 < 27) atomicAdd(omb + ((size_t)o1 << 14), acc1[j]);
    }
}

// ---------------- Kernel 3: FUSED deform-gather + bf16 MFMA GEMM, full K=2304 ----------------
// grid 512 (XCD-swizzled) = 64-pos tiles; block 256 = 4 waves; M=256 o, N=64 pos.
// Per 64-K step: each thread gathers 2 pos x 8 ch from Xt (bilinear, 4 corners x 16B),
// packs bf16, writes LINEAR to LDS at tid*16 (+4096); the read-side XOR swizzle is
// absorbed into which k-slice the thread computes (kloc8). ds_read side identical to
// the verified k_gemm.
__global__ __launch_bounds__(256) void k_sgemm(const u16* __restrict__ Xt,
                                               const float* __restrict__ om,
                                               const u16* __restrict__ wfr,
                                               const float* __restrict__ bias,
                                               float* __restrict__ y) {
    __shared__ int4   soff[9][64];
    __shared__ float4 swt[9][64];
    __shared__ u16    Blds[2][4096];

    const int tid  = threadIdx.x;
    const int wid  = tid >> 6;
    const int lane = tid & 63;
    const int bid  = ((blockIdx.x & 7) << 6) | (blockIdx.x >> 3);  // XCD swizzle, 512 = 8*64
    const int p0   = bid * 64;
    const int b    = p0 >> 14;
    const int hwb  = p0 & 16383;

    // ---- coords: 64 pos x 9 taps ----
    for (int e = tid; e < 576; e += 256) {
        int t = e >> 6, j = e & 63;
        int hw = hwb + j;
        int h = hw >> 7, wc = hw & 127;
        const size_t ob = (size_t)b * 27 * HW;
        float oy = om[ob + (size_t)t * HW + hw];
        float ox = om[ob + (size_t)(9 + t) * HW + hw];
        float mv = om[ob + (size_t)(18 + t) * HW + hw];
        mv = 1.0f / (1.0f + expf(-mv));
        float py = (float)h - 1.0f + (float)(t / 3) + oy;
        float px = (float)wc - 1.0f + (float)(t % 3) + ox;
        float y0f = floorf(py), x0f = floorf(px);
        float wy = py - y0f, wx = px - x0f;
        int iy = (int)y0f, ix = (int)x0f;
        float w4[4] = {(1.0f - wy) * (1.0f - wx), (1.0f - wy) * wx,
                       wy * (1.0f - wx),          wy * wx};
        const int dy[4] = {0, 0, 1, 1};
        const int dx[4] = {0, 1, 0, 1};
        int of[4]; float cw[4];
        #pragma unroll
        for (int r = 0; r < 4; ++r) {
            int yy = iy + dy[r], xx = ix + dx[r];
            bool v = (yy >= 0) && (yy <= 127) && (xx >= 0) && (xx <= 127);
            int yc = min(max(yy, 0), 127);
            int xc = min(max(xx, 0), 127);
            of[r] = yc * 128 + xc;
            cw[r] = v ? w4[r] * mv : 0.0f;
        }
        soff[t][j] = make_int4(of[0], of[1], of[2], of[3]);
        swt[t][j]  = make_float4(cw[0], cw[1], cw[2], cw[3]);
    }
    __syncthreads();

    const int jp    = tid >> 3;                        // pos rows jp and jp+32
    const int kloc8 = (((tid & 7) ^ (jp & 7)) << 3);   // pre-swizzled 8-ch k-slice
    const u16* XtB  = Xt + (((size_t)b << 14) << 8);

    const int lg = lane >> 4;
    const int lr = lane & 15;

    f32x4 acc[4][4];
    #pragma unroll
    for (int m = 0; m < 4; ++m)
        #pragma unroll
        for (int n = 0; n < 4; ++n) acc[m][n] = (f32x4)0.0f;

    auto gload = [&](int s, uint4* gg) {
        int t = s >> 2;
        int c = ((s & 3) << 6) + kloc8;
        int4 oa = soff[t][jp];
        int4 ob2 = soff[t][jp + 32];
        gg[0] = *(const uint4*)(XtB + (size_t)oa.x * 256 + c);
        gg[1] = *(const uint4*)(XtB + (size_t)oa.y * 256 + c);
        gg[2] = *(const uint4*)(XtB + (size_t)oa.z * 256 + c);
        gg[3] = *(const uint4*)(XtB + (size_t)oa.w * 256 + c);
        gg[4] = *(const uint4*)(XtB + (size_t)ob2.x * 256 + c);
        gg[5] = *(const uint4*)(XtB + (size_t)ob2.y * 256 + c);
        gg[6] = *(const uint4*)(XtB + (size_t)ob2.z * 256 + c);
        gg[7] = *(const uint4*)(XtB + (size_t)ob2.w * 256 + c);
    };
    auto gcomb = [&](int s, const uint4* gg, int buf) {
        int t = s >> 2;
        float4 ca = swt[t][jp];
        float4 cb = swt[t][jp + 32];
        const u32* gw = (const u32*)gg;
        u32 oa[4], ob3[4];
        #pragma unroll
        for (int q = 0; q < 4; ++q) {
            float lo = ca.x * bl(gw[q])      + ca.y * bl(gw[4 + q])
                     + ca.z * bl(gw[8 + q])  + ca.w * bl(gw[12 + q]);
            float hi = ca.x * bh(gw[q])      + ca.y * bh(gw[4 + q])
                     + ca.z * bh(gw[8 + q])  + ca.w * bh(gw[12 + q]);
            oa[q] = pkbf(lo, hi);
            float lo2 = cb.x * bl(gw[16 + q]) + cb.y * bl(gw[20 + q])
                      + cb.z * bl(gw[24 + q]) + cb.w * bl(gw[28 + q]);
            float hi2 = cb.x * bh(gw[16 + q]) + cb.y * bh(gw[20 + q])
                      + cb.z * bh(gw[24 + q]) + cb.w * bh(gw[28 + q]);
            ob3[q] = pkbf(lo2, hi2);
        }
        char* dst = (char*)&Blds[buf][0] + tid * 16;
        *(uint4*)dst          = make_uint4(oa[0], oa[1], oa[2], oa[3]);
        *(uint4*)(dst + 4096) = make_uint4(ob3[0], ob3[1], ob3[2], ob3[3]);
    };
    auto aload = [&](int k32g, bf16x8 dst2[2][4]) {
        #pragma unroll
        for (int kk = 0; kk < 2; ++kk)
            #pragma unroll
            for (int m = 0; m < 4; ++m)
                dst2[kk][m] = *(const bf16x8*)(wfr +
                    ((size_t)((wid * 4 + m) * 72 + k32g + kk) << 9) + (size_t)lane * 8);
    };

    bf16x8 af[2][4];
    // ---- prologue: step 0 ----
    {
        uint4 g[8];
        gload(0, g);
        aload(0, af);
        gcomb(0, g, 0);
    }
    __syncthreads();

    int cur = 0;
    for (int s = 0; s < 36; ++s) {
        const int nxt = cur ^ 1;
        uint4 gn[8];
        bf16x8 afn[2][4];
        if (s < 35) {
            gload(s + 1, gn);
            aload(2 * (s + 1), afn);
        }

        const char* bb2 = (const char*)&Blds[cur][0];
        #pragma unroll
        for (int kk = 0; kk < 2; ++kk) {
            bf16x8 bfv[4];
            #pragma unroll
            for (int n = 0; n < 4; ++n) {
                int row  = n * 16 + lr;
                int boff = row * 128 + ((kk * 64 + lg * 16) ^ ((row & 7) << 4));
                bfv[n] = *(const bf16x8*)(bb2 + boff);
            }
            #pragma unroll
            for (int m = 0; m < 4; ++m)
                #pragma unroll
                for (int n = 0; n < 4; ++n)
                    acc[m][n] = __builtin_amdgcn_mfma_f32_16x16x32_bf16(af[kk][m], bfv[n], acc[m][n], 0, 0, 0);
        }

        if (s < 35) {
            gcomb(s + 1, gn, nxt);
            #pragma unroll
            for (int kk = 0; kk < 2; ++kk)
                #pragma unroll
                for (int m = 0; m < 4; ++m)
                    af[kk][m] = afn[kk][m];
        }
        __syncthreads();
        cur = nxt;
    }

    // ---- epilogue: bias + write y ----
    const int hw0 = hwb + lr;
    #pragma unroll
    for (int m = 0; m < 4; ++m) {
        #pragma unroll
        for (int jj = 0; jj < 4; ++jj) {
            int o = wid * 64 + m * 16 + lg * 4 + jj;
            float bv = bias[o];
            float* ya = y + ((size_t)b * 256 + o) * HW + hw0;
            #pragma unroll
            for (int n = 0; n < 4; ++n)
                ya[n * 16] = acc[m][n][jj] + bv;
        }
    }
}

// ---------------- Kernel 4: per-channel mean/var ----------------
__global__ void k_stats(const float* __restrict__ y, float* __restrict__ stats) {
    int o   = blockIdx.x;
    int tid = threadIdx.x;
    float s = 0.0f, sq = 0.0f;
    const float* y0 = y + (size_t)o * HW;
    const float* y1 = y + (size_t)(CO + o) * HW;
    for (int i = tid; i < HW; i += 256) {
        float v = y0[i]; s += v; sq += v * v;
        v = y1[i];       s += v; sq += v * v;
    }
    __shared__ float rs[256], rq[256];
    rs[tid] = s; rq[tid] = sq;
    __syncthreads();
    for (int st = 128; st > 0; st >>= 1) {
        if (tid < st) { rs[tid] += rs[tid + st]; rq[tid] += rq[tid + st]; }
        __syncthreads();
    }
    if (tid == 0) {
        float mu  = rs[0] / 32768.0f;
        float var = rq[0] / 32768.0f - mu * mu;
        stats[o]       = mu;
        stats[256 + o] = rsqrtf(var + 1e-5f);
    }
}

// ---------------- Kernel 5: normalize + relu ----------------
__global__ void k_norm(const float* __restrict__ y, const float* __restrict__ stats,
                       const float* __restrict__ gamma, const float* __restrict__ beta,
                       float* __restrict__ out) {
    int i4 = blockIdx.x * 256 + threadIdx.x;
    if (i4 >= (2 * CO * HW) / 4) return;
    int o = (i4 >> 12) & 255;
    float g  = gamma[o] * stats[256 + o];
    float bt = beta[o] - stats[o] * g;
    float4 v = ((const float4*)y)[i4];
    float4 r;
    r.x = fmaxf(fmaf(v.x, g, bt), 0.0f);
    r.y = fmaxf(fmaf(v.y, g, bt), 0.0f);
    r.z = fmaxf(fmaf(v.z, g, bt), 0.0f);
    r.w = fmaxf(fmaf(v.w, g, bt), 0.0f);
    ((float4*)out)[i4] = r;
}

extern "C" void kernel_launch(void* const* d_in, const int* in_sizes, int n_in,
                              void* d_out, int out_size, void* d_ws, size_t ws_size,
                              hipStream_t stream) {
    const float* x      = (const float*)d_in[0];
    const float* w_off  = (const float*)d_in[1];
    const float* b_off  = (const float*)d_in[2];
    const float* weight = (const float*)d_in[3];
    const float* bias   = (const float*)d_in[4];
    const float* gamma  = (const float*)d_in[5];
    const float* beta   = (const float*)d_in[6];
    float* out = (float*)d_out;

    float* ws   = (float*)d_ws;
    float* om   = ws;                        // 884736 f
    float* st   = om + 884736;               // 512 f
    float* yb   = st + 512;                  // 8388608 f
    u16*   wfr  = (u16*)(yb + 8388608);      // 589824 u16
    u16*   wofr = wfr + 589824;              // 73728 u16
    u16*   Xt   = wofr + 73728;              // 8388608 u16 (16.8 MB)

    k_wbf<<<2304, 256, 0, stream>>>(weight, wfr);
    k_wof_fr<<<288, 256, 0, stream>>>(w_off, wofr);
    k_xt<<<512, 256, 0, stream>>>(x, Xt);
    k_ominit<<<3456, 256, 0, stream>>>(b_off, om);
    k_offmfma<<<2048, 256, 0, stream>>>(Xt, wofr, om);

    k_sgemm<<<512, 256, 0, stream>>>(Xt, om, wfr, bias, yb);

    k_stats<<<CO, 256, 0, stream>>>(yb, st);
    k_norm<<<(2 * CO * HW / 4 + 255) / 256, 256, 0, stream>>>(yb, st, gamma, beta, out);
}